// Round 5
// baseline (336.877 us; speedup 1.0000x reference)
//
#include <hip/hip_runtime.h>
#include <math.h>

#define GRIDN 64
#define MAXE 32
#define MAXPRIM 1024
#define EROW 36        // ints per entry row: [cnt, e0..e31, pad x3]
#define CSTRIDE 32     // counter padding: one counter per 128B line
#define OVFCAP 16384

// workspace layout (bytes)
#define WS_PACKED2   0u
#define WS_COLORS    32768u
#define WS_ETAB      49152u        // 4096*36*4 = 589824 -> ends 638976
#define WS_COUNTERS  655360u       // 4096*32*4 = 524288 -> ends 1179648
#define WS_OVFCNT    1179648u
#define WS_OVFLIST   1179712u      // 16384*4 -> ends 1245248
#define WS_BINIDX    1310720u      // 4096*CAP*4

// exact core: t = rn(td/denom) (via double-recip mul), s2 <= Tf <=> rn(sqrt(s2)) <= w
#define CORE_EVAL(A, Bv)                                                         \
    float relx = __fsub_rn(px, A.x);                                             \
    float rely = __fsub_rn(py, A.y);                                             \
    float td = __fadd_rn(__fmul_rn(relx, A.z), __fmul_rn(rely, A.w));            \
    double inv = __hiloint2double(__float_as_int(Bv.z), __float_as_int(Bv.y));   \
    float tt = (float)((double)td * inv);                                        \
    tt = fminf(fmaxf(tt, 0.0f), 1.0f);                                           \
    float qx = __fsub_rn(relx, __fmul_rn(tt, A.z));                              \
    float qy = __fsub_rn(rely, __fmul_rn(tt, A.w));                              \
    float s2 = __fadd_rn(__fmul_rn(qx, qx), __fmul_rn(qy, qy));

// ---------------------------------------------------------------------------
// Kernel 1: prep — grid build (one wave per cell, AABBs in LDS), pack (block 0),
// counter/overflow zeroing (block 1).
// ---------------------------------------------------------------------------
__global__ __launch_bounds__(1024) void prep(const float* __restrict__ cp,
                                             const float* __restrict__ sw,
                                             const float* __restrict__ fc,
                                             const float* __restrict__ op,
                                             float4* __restrict__ packed2,
                                             float4* __restrict__ colors,
                                             int* __restrict__ etab,
                                             int* __restrict__ counters,
                                             int* __restrict__ ovfcnt, int nprim) {
    __shared__ float4 saabb[MAXPRIM];
    int tid = threadIdx.x;
    for (int p = tid; p < nprim; p += 1024) {
        float x0 = cp[p * 6 + 0], y0 = cp[p * 6 + 1];
        float x1 = cp[p * 6 + 2], y1 = cp[p * 6 + 3];
        float w = sw[p];
        saabb[p] = make_float4(__fsub_rn(fminf(x0, x1), w), __fadd_rn(fmaxf(x0, x1), w),
                               __fsub_rn(fminf(y0, y1), w), __fadd_rn(fmaxf(y0, y1), w));
    }
    __syncthreads();

    int wid = tid >> 6, lane = tid & 63;
    int cell = blockIdx.x * 16 + wid;
    int ixc = cell >> 6, iyc = cell & 63;
    float lox = (float)ixc * (1.0f / GRIDN);
    float hix = (float)(ixc + 1) * (1.0f / GRIDN);
    float loy = (float)iyc * (1.0f / GRIDN);
    float hiy = (float)(iyc + 1) * (1.0f / GRIDN);
    int total = 0;
    int* row = etab + (size_t)cell * EROW;
    for (int base = 0; base < nprim; base += 64) {
        int p = base + lane;
        bool ov = false;
        if (p < nprim) {
            float4 bb = saabb[p];
            ov = (bb.x < hix) && (bb.y >= lox) && (bb.z < hiy) && (bb.w >= loy);
        }
        unsigned long long m = __ballot(ov);
        if (ov) {
            int pos = total + (int)__popcll(m & ((1ull << lane) - 1ull));
            if (pos < MAXE) row[1 + pos] = p;
        }
        total += (int)__popcll(m);
    }
    if (lane == 0) row[0] = total < MAXE ? total : MAXE;

    if (blockIdx.x == 0) {
        for (int p = tid; p < nprim; p += 1024) {
            float x0 = cp[p * 6 + 0], y0 = cp[p * 6 + 1];
            float x1 = cp[p * 6 + 2], y1 = cp[p * 6 + 3];
            float w = sw[p];
            float dx = __fsub_rn(x1, x0);
            float dy = __fsub_rn(y1, y0);
            float dd = __fadd_rn(__fmul_rn(dx, dx), __fmul_rn(dy, dy));
            float denom = fmaxf(dd, 1e-12f);
            double inv = 1.0 / (double)denom;
            unsigned wb = __float_as_uint(w);
            bool even = (wb & 1u) == 0u;
            float wn = __uint_as_float(wb + 1u);
            double md = 0.5 * ((double)w + (double)wn);
            double m2 = md * md;
            float Tf = (float)m2;
            if ((double)Tf > m2) Tf = __uint_as_float(__float_as_uint(Tf) - 1u);
            if (!even && (double)Tf == m2) Tf = __uint_as_float(__float_as_uint(Tf) - 1u);
            unsigned long long ib = __double_as_longlong(inv);
            packed2[p * 2 + 0] = make_float4(x0, y0, dx, dy);
            packed2[p * 2 + 1] = make_float4(Tf,
                                             __uint_as_float((unsigned)(ib & 0xffffffffull)),
                                             __uint_as_float((unsigned)(ib >> 32)),
                                             0.0f);
            colors[p] = make_float4(fc[p * 3 + 0], fc[p * 3 + 1], fc[p * 3 + 2], op[p]);
        }
    }
    if (blockIdx.x == 1) {
        for (int k = tid; k < GRIDN * GRIDN; k += 1024) counters[k * CSTRIDE] = 0;
        if (tid == 0) ovfcnt[0] = 0;
    }
}

// ---------------------------------------------------------------------------
// Kernel 2: bin points by cell (capacity-strided bins, padded counters).
// ---------------------------------------------------------------------------
__global__ __launch_bounds__(256) void bin_points(const float2* __restrict__ xs,
                                                  int* __restrict__ counters,
                                                  int* __restrict__ binidx, int cap,
                                                  int* __restrict__ ovfcnt,
                                                  int* __restrict__ ovflist, int npts) {
    int i = blockIdx.x * 256 + threadIdx.x;
    if (i >= npts) return;
    float2 P = xs[i];
    int ix = (int)__fmul_rn(P.x, (float)GRIDN);
    ix = min(max(ix, 0), GRIDN - 1);
    int iy = (int)__fmul_rn(P.y, (float)GRIDN);
    iy = min(max(iy, 0), GRIDN - 1);
    int cell = ix * GRIDN + iy;
    int pos = atomicAdd(&counters[cell * CSTRIDE], 1);
    if (pos < cap) {
        binidx[(size_t)cell * cap + pos] = i;
    } else {
        int o = atomicAdd(ovfcnt, 1);
        if (o < OVFCAP) ovflist[o] = i;
    }
}

// ---------------------------------------------------------------------------
// Kernel 3: render, one block per cell. Uniform prim loop (no divergence),
// wave-uniform LDS broadcasts (no bank conflicts). Overflow tail = generic
// per-point composite with global prim reads.
// ---------------------------------------------------------------------------
__global__ __launch_bounds__(256) void render_binned(const float2* __restrict__ xs,
                                                     const float4* __restrict__ packed2,
                                                     const float4* __restrict__ colors,
                                                     const int* __restrict__ etab,
                                                     const int* __restrict__ counters,
                                                     const int* __restrict__ binidx, int cap,
                                                     const int* __restrict__ ovfcnt,
                                                     const int* __restrict__ ovflist,
                                                     const float* __restrict__ bg,
                                                     float* __restrict__ out, int npts) {
    __shared__ float4 sA[MAXE], sB[MAXE], scol[MAXE];
    __shared__ int sflag;
    int cell = blockIdx.x;
    int tid = threadIdx.x;
    const int* row = etab + (size_t)cell * EROW;
    int cnt = row[0];                       // uniform (scalar) load
    int ptc = counters[cell * CSTRIDE];
    if (ptc > cap) ptc = cap;

    bool bad = false;
    if (tid < cnt) {
        int e = row[1 + tid];
        sA[tid] = packed2[e * 2 + 0];
        sB[tid] = packed2[e * 2 + 1];
        float4 c = colors[e];
        scol[tid] = c;
        if (c.w != 1.0f) bad = true;
    }
    if (tid < 64) {
        unsigned long long m = __ballot(bad);
        if (tid == 0) sflag = (m != 0ull) ? 1 : 0;
    }
    __syncthreads();
    int flag = sflag;

    float bgr = bg[0], bgg = bg[1], bgb = bg[2];
    const int* bin = binidx + (size_t)cell * cap;

    for (int j = tid; j < ptc; j += 256) {
        int i = bin[j];
        float2 P = xs[i];
        float px = P.x, py = P.y;
        float cr, cg, cb;
        if (!flag) {
            int win = -1;
            for (int s = 0; s < cnt; ++s) {
                float4 A = sA[s];
                float4 Bv = sB[s];
                CORE_EVAL(A, Bv);
                if (s2 <= Bv.x) win = s;
            }
            if (win >= 0) {
                float4 C = scol[win];
                cr = C.x; cg = C.y; cb = C.z;
            } else {
                cr = bgr; cg = bgg; cb = bgb;
            }
        } else {
            cr = bgr; cg = bgg; cb = bgb;
            for (int s = 0; s < cnt; ++s) {
                float4 A = sA[s];
                float4 Bv = sB[s];
                CORE_EVAL(A, Bv);
                float4 C = scol[s];
                float a = (s2 <= Bv.x) ? C.w : 0.0f;
                float om = __fsub_rn(1.0f, a);
                cr = __fadd_rn(__fmul_rn(cr, om), __fmul_rn(C.x, a));
                cg = __fadd_rn(__fmul_rn(cg, om), __fmul_rn(C.y, a));
                cb = __fadd_rn(__fmul_rn(cb, om), __fmul_rn(C.z, a));
            }
        }
        float3 o; o.x = cr; o.y = cg; o.z = cb;
        *(float3*)(out + (size_t)i * 3) = o;
    }

    // overflow tail (normally empty)
    int novf = ovfcnt[0];
    if (novf > OVFCAP) novf = OVFCAP;
    int k = blockIdx.x * 256 + tid;
    if (k < novf) {
        int i = ovflist[k];
        float2 P = xs[i];
        float px = P.x, py = P.y;
        int ix = (int)__fmul_rn(px, (float)GRIDN);
        ix = min(max(ix, 0), GRIDN - 1);
        int iy = (int)__fmul_rn(py, (float)GRIDN);
        iy = min(max(iy, 0), GRIDN - 1);
        const int* prow = etab + (size_t)(ix * GRIDN + iy) * EROW;
        int pcnt = prow[0];
        float cr = bgr, cg = bgg, cb = bgb;
        for (int s = 0; s < pcnt; ++s) {
            int e = prow[1 + s];
            float4 A = packed2[e * 2 + 0];
            float4 Bv = packed2[e * 2 + 1];
            CORE_EVAL(A, Bv);
            float4 C = colors[e];
            float a = (s2 <= Bv.x) ? C.w : 0.0f;
            float om = __fsub_rn(1.0f, a);
            cr = __fadd_rn(__fmul_rn(cr, om), __fmul_rn(C.x, a));
            cg = __fadd_rn(__fmul_rn(cg, om), __fmul_rn(C.y, a));
            cb = __fadd_rn(__fmul_rn(cb, om), __fmul_rn(C.z, a));
        }
        out[(size_t)i * 3 + 0] = cr;
        out[(size_t)i * 3 + 1] = cg;
        out[(size_t)i * 3 + 2] = cb;
    }
}

// ---------------------------------------------------------------------------
// Fallback render (round-4 kernel) for small ws_size: full LDS prim table.
// ---------------------------------------------------------------------------
__global__ __launch_bounds__(1024) void render_fb(const float2* __restrict__ xs,
                                                  const float4* __restrict__ packed2,
                                                  const float4* __restrict__ colors,
                                                  const int* __restrict__ etab,
                                                  const float* __restrict__ bg,
                                                  float* __restrict__ out, int n, int nprim) {
    __shared__ float4 sAB[MAXPRIM * 2];
    __shared__ float4 scol[MAXPRIM];
    __shared__ int sflag;
    if (threadIdx.x == 0) sflag = 0;
    __syncthreads();

    int i = blockIdx.x * 1024 + threadIdx.x;
    bool valid = i < n;
    float px = 0.0f, py = 0.0f;
    int row = 0;
    int4 c0 = make_int4(0, 0, 0, 0), c1 = make_int4(0, 0, 0, 0);
    if (valid) {
        float2 pxy = xs[i];
        px = pxy.x; py = pxy.y;
        int ix = (int)__fmul_rn(px, (float)GRIDN);
        ix = min(max(ix, 0), GRIDN - 1);
        int iy = (int)__fmul_rn(py, (float)GRIDN);
        iy = min(max(iy, 0), GRIDN - 1);
        row = (ix * GRIDN + iy) * EROW;
        c0 = *(const int4*)(etab + row);
        c1 = *(const int4*)(etab + row + 4);
    }
    for (int t = threadIdx.x; t < nprim; t += 1024) {
        sAB[t * 2 + 0] = packed2[t * 2 + 0];
        sAB[t * 2 + 1] = packed2[t * 2 + 1];
        float4 c = colors[t];
        scol[t] = c;
        if (c.w != 1.0f) sflag = 1;
    }
    __syncthreads();
    int cnt = valid ? c0.x : 0;

    float cr = bg[0], cg = bg[1], cb = bg[2];
    int win = -1;
    bool fast = (sflag == 0);
#define TEST(pidx)                                                             \
    {                                                                          \
        int p = (pidx);                                                        \
        float4 A = sAB[p * 2 + 0];                                             \
        float4 Bv = sAB[p * 2 + 1];                                            \
        CORE_EVAL(A, Bv);                                                      \
        if (fast) {                                                            \
            if (s2 <= Bv.x) win = p;                                           \
        } else {                                                               \
            float4 C = scol[p];                                                \
            float a = (s2 <= Bv.x) ? C.w : 0.0f;                               \
            float om = __fsub_rn(1.0f, a);                                     \
            cr = __fadd_rn(__fmul_rn(cr, om), __fmul_rn(C.x, a));              \
            cg = __fadd_rn(__fmul_rn(cg, om), __fmul_rn(C.y, a));              \
            cb = __fadd_rn(__fmul_rn(cb, om), __fmul_rn(C.z, a));              \
        }                                                                      \
    }
    if (cnt > 0) TEST(c0.y);
    if (cnt > 1) TEST(c0.z);
    if (cnt > 2) TEST(c0.w);
    if (cnt > 3) TEST(c1.x);
    if (cnt > 4) TEST(c1.y);
    if (cnt > 5) TEST(c1.z);
    if (cnt > 6) TEST(c1.w);
    for (int base = 7; base < cnt; base += 4) {
        int4 c = *(const int4*)(etab + row + 1 + base);
        if (base + 0 < cnt) TEST(c.x);
        if (base + 1 < cnt) TEST(c.y);
        if (base + 2 < cnt) TEST(c.z);
        if (base + 3 < cnt) TEST(c.w);
    }
#undef TEST
    if (valid) {
        if (fast && win >= 0) {
            float4 C = scol[win];
            cr = C.x; cg = C.y; cb = C.z;
        }
        out[(size_t)i * 3 + 0] = cr;
        out[(size_t)i * 3 + 1] = cg;
        out[(size_t)i * 3 + 2] = cb;
    }
}

extern "C" void kernel_launch(void* const* d_in, const int* in_sizes, int n_in,
                              void* d_out, int out_size, void* d_ws, size_t ws_size,
                              hipStream_t stream) {
    const float* x  = (const float*)d_in[0];
    const float* cp = (const float*)d_in[1];
    const float* sw = (const float*)d_in[2];
    const float* fc = (const float*)d_in[3];
    const float* op = (const float*)d_in[4];
    const float* bg = (const float*)d_in[5];
    float* out = (float*)d_out;

    int npts  = in_sizes[0] / 2;
    int nprim = in_sizes[2];

    char* ws = (char*)d_ws;
    float4* packed2 = (float4*)(ws + WS_PACKED2);
    float4* colors  = (float4*)(ws + WS_COLORS);
    int* etab       = (int*)(ws + WS_ETAB);
    int* counters   = (int*)(ws + WS_COUNTERS);
    int* ovfcnt     = (int*)(ws + WS_OVFCNT);
    int* ovflist    = (int*)(ws + WS_OVFLIST);
    int* binidx     = (int*)(ws + WS_BINIDX);

    long long per = (npts + GRIDN * GRIDN - 1) / (GRIDN * GRIDN);
    int cap = (int)(per + per / 3 + 64);
    cap = (cap + 3) & ~3;
    size_t need = (size_t)WS_BINIDX + (size_t)GRIDN * GRIDN * (size_t)cap * 4u;
    bool binned = (ws_size >= need);

    prep<<<GRIDN * GRIDN / 16, 1024, 0, stream>>>(cp, sw, fc, op, packed2, colors,
                                                  etab, counters, ovfcnt, nprim);
    if (binned) {
        bin_points<<<(npts + 255) / 256, 256, 0, stream>>>((const float2*)x, counters,
                                                           binidx, cap, ovfcnt, ovflist, npts);
        render_binned<<<GRIDN * GRIDN, 256, 0, stream>>>((const float2*)x, packed2, colors,
                                                         etab, counters, binidx, cap,
                                                         ovfcnt, ovflist, bg, out, npts);
    } else {
        render_fb<<<(npts + 1023) / 1024, 1024, 0, stream>>>((const float2*)x, packed2, colors,
                                                             etab, bg, out, npts, nprim);
    }
}

// Round 6
// 69.955 us; speedup vs baseline: 4.8156x; 4.8156x over previous
//
#include <hip/hip_runtime.h>
#include <math.h>

#define GRIDN 64
#define MAXE 32
#define MAXPRIM 1024
#define EROW 36        // parent row: [cnt, e0..e31, pad x3]
#define SROW 16        // subgrid row: [cnt, e0..e14]
#define SCAP 15
#define SENT 0x7fff
#define SUBD 1e-5f     // prune safety margin >> float rounding skin

// workspace layout (bytes)
#define WS_PACKED2   0u            // 1024*32
#define WS_COLORS    32768u        // 1024*16
#define WS_AABB      49152u        // 1024*16
#define WS_ETAB      65536u        // 4096*36*4 = 589824 -> ends 655360
#define WS_SUBTAB    655360u       // 65536*16*4 = 4194304 -> ends 4849664

// exact core: t = rn(td/denom) (double-recip mul), s2 <= Tf <=> rn(sqrt(s2)) <= w
#define CORE_EVAL(A, Bv)                                                         \
    float relx = __fsub_rn(px, A.x);                                             \
    float rely = __fsub_rn(py, A.y);                                             \
    float td = __fadd_rn(__fmul_rn(relx, A.z), __fmul_rn(rely, A.w));            \
    double inv = __hiloint2double(__float_as_int(Bv.z), __float_as_int(Bv.y));   \
    float tt = (float)((double)td * inv);                                        \
    tt = fminf(fmaxf(tt, 0.0f), 1.0f);                                           \
    float qx = __fsub_rn(relx, __fmul_rn(tt, A.z));                              \
    float qy = __fsub_rn(rely, __fmul_rn(tt, A.w));                              \
    float s2 = __fadd_rn(__fmul_rn(qx, qx), __fmul_rn(qy, qy));

// ---------------------------------------------------------------------------
// Kernel 1: prep — parent grid build (one wave per cell, AABBs in LDS);
// block 0 additionally packs prim records and stores AABBs to global.
// ---------------------------------------------------------------------------
__global__ __launch_bounds__(1024) void prep(const float* __restrict__ cp,
                                             const float* __restrict__ sw,
                                             const float* __restrict__ fc,
                                             const float* __restrict__ op,
                                             float4* __restrict__ packed2,
                                             float4* __restrict__ colors,
                                             float4* __restrict__ aabb_g,
                                             int* __restrict__ etab, int nprim) {
    __shared__ float4 saabb[MAXPRIM];
    int tid = threadIdx.x;
    for (int p = tid; p < nprim; p += 1024) {
        float x0 = cp[p * 6 + 0], y0 = cp[p * 6 + 1];
        float x1 = cp[p * 6 + 2], y1 = cp[p * 6 + 3];
        float w = sw[p];
        saabb[p] = make_float4(__fsub_rn(fminf(x0, x1), w), __fadd_rn(fmaxf(x0, x1), w),
                               __fsub_rn(fminf(y0, y1), w), __fadd_rn(fmaxf(y0, y1), w));
    }
    __syncthreads();

    int wid = tid >> 6, lane = tid & 63;
    int cell = blockIdx.x * 16 + wid;
    int ixc = cell >> 6, iyc = cell & 63;
    float lox = (float)ixc * (1.0f / GRIDN);
    float hix = (float)(ixc + 1) * (1.0f / GRIDN);
    float loy = (float)iyc * (1.0f / GRIDN);
    float hiy = (float)(iyc + 1) * (1.0f / GRIDN);
    int total = 0;
    int* row = etab + (size_t)cell * EROW;
    for (int base = 0; base < nprim; base += 64) {
        int p = base + lane;
        bool ov = false;
        if (p < nprim) {
            float4 bb = saabb[p];
            ov = (bb.x < hix) && (bb.y >= lox) && (bb.z < hiy) && (bb.w >= loy);
        }
        unsigned long long m = __ballot(ov);
        if (ov) {
            int pos = total + (int)__popcll(m & ((1ull << lane) - 1ull));
            if (pos < MAXE) row[1 + pos] = p;
        }
        total += (int)__popcll(m);
    }
    if (lane == 0) row[0] = total < MAXE ? total : MAXE;

    if (blockIdx.x == 0) {
        for (int p = tid; p < nprim; p += 1024) {
            float x0 = cp[p * 6 + 0], y0 = cp[p * 6 + 1];
            float x1 = cp[p * 6 + 2], y1 = cp[p * 6 + 3];
            float w = sw[p];
            float dx = __fsub_rn(x1, x0);
            float dy = __fsub_rn(y1, y0);
            float dd = __fadd_rn(__fmul_rn(dx, dx), __fmul_rn(dy, dy));
            float denom = fmaxf(dd, 1e-12f);
            double inv = 1.0 / (double)denom;
            unsigned wb = __float_as_uint(w);
            bool even = (wb & 1u) == 0u;
            float wn = __uint_as_float(wb + 1u);
            double md = 0.5 * ((double)w + (double)wn);
            double m2 = md * md;
            float Tf = (float)m2;
            if ((double)Tf > m2) Tf = __uint_as_float(__float_as_uint(Tf) - 1u);
            if (!even && (double)Tf == m2) Tf = __uint_as_float(__float_as_uint(Tf) - 1u);
            unsigned long long ib = __double_as_longlong(inv);
            packed2[p * 2 + 0] = make_float4(x0, y0, dx, dy);
            packed2[p * 2 + 1] = make_float4(Tf,
                                             __uint_as_float((unsigned)(ib & 0xffffffffull)),
                                             __uint_as_float((unsigned)(ib >> 32)),
                                             0.0f);
            colors[p] = make_float4(fc[p * 3 + 0], fc[p * 3 + 1], fc[p * 3 + 2], op[p]);
            aabb_g[p] = saabb[p];
        }
    }
}

// ---------------------------------------------------------------------------
// Kernel 2: build 256x256 subgrid by pruning each parent cell's list against
// the 4x4 subcells (margin SUBD). One thread per subcell; 16 consecutive
// threads share a parent (broadcast reads). Ascending order preserved.
// ---------------------------------------------------------------------------
__global__ __launch_bounds__(1024) void build_sub(const float4* __restrict__ aabb_g,
                                                  const int* __restrict__ etab,
                                                  int* __restrict__ subtab) {
    int t = blockIdx.x * 1024 + threadIdx.x;   // 64 blocks x 1024 = 65536
    int parent = t >> 4;
    int sub = t & 15;
    int ix = parent >> 6, iy = parent & 63;
    int sx = sub >> 2, sy = sub & 3;
    int gx = ix * 4 + sx, gy = iy * 4 + sy;
    float lox = (float)gx * (1.0f / 256.0f);
    float hix = (float)(gx + 1) * (1.0f / 256.0f);
    float loy = (float)gy * (1.0f / 256.0f);
    float hiy = (float)(gy + 1) * (1.0f / 256.0f);
    const int* row = etab + (size_t)parent * EROW;
    int cnt = row[0];
    int* srow = subtab + (size_t)(gx * 256 + gy) * SROW;
    int oc = 0;
    for (int s = 0; s < cnt; ++s) {
        int e = row[1 + s];
        float4 bb = aabb_g[e];
        bool ov = (bb.x < hix + SUBD) && (bb.y >= lox - SUBD) &&
                  (bb.z < hiy + SUBD) && (bb.w >= loy - SUBD);
        if (ov) {
            if (oc < SCAP) srow[1 + oc] = e;
            ++oc;
        }
    }
    srow[0] = (oc <= SCAP) ? oc : SENT;
}

// ---------------------------------------------------------------------------
// Kernel 3: render via subgrid. Prim records in LDS (B-array skewed +64B so a
// slot's two b128 gathers hit disjoint bank groups). Subcell derived from the
// reference's own parent index, so parent cell always agrees.
// ---------------------------------------------------------------------------
__global__ __launch_bounds__(1024) void render_sub(const float2* __restrict__ xs,
                                                   const float4* __restrict__ packed2,
                                                   const float4* __restrict__ colors,
                                                   const int* __restrict__ etab,
                                                   const int* __restrict__ subtab,
                                                   const float* __restrict__ bg,
                                                   float* __restrict__ out, int n, int nprim) {
    __shared__ float4 sA[MAXPRIM];
    __shared__ float4 sBsk[MAXPRIM + 4];   // +4 float4 = 64B skew
    __shared__ float4 scol[MAXPRIM];
    __shared__ int sflag;
    if (threadIdx.x == 0) sflag = 0;
    __syncthreads();

    int i = blockIdx.x * 1024 + threadIdx.x;
    bool valid = i < n;
    float px = 0.0f, py = 0.0f;
    int parent = 0;
    int4 h0 = make_int4(0, 0, 0, 0);
    const int* srow = subtab;
    if (valid) {
        float2 P = xs[i];
        px = P.x; py = P.y;
        int ix = (int)__fmul_rn(px, (float)GRIDN);
        ix = min(max(ix, 0), GRIDN - 1);
        int iy = (int)__fmul_rn(py, (float)GRIDN);
        iy = min(max(iy, 0), GRIDN - 1);
        parent = ix * GRIDN + iy;
        int sx = (int)__fmul_rn(px, 256.0f) - ix * 4;
        sx = min(max(sx, 0), 3);
        int sy = (int)__fmul_rn(py, 256.0f) - iy * 4;
        sy = min(max(sy, 0), 3);
        srow = subtab + (size_t)((ix * 4 + sx) * 256 + (iy * 4 + sy)) * SROW;
        h0 = *(const int4*)srow;       // cnt, e0, e1, e2
    }

    for (int t = threadIdx.x; t < nprim; t += 1024) {
        sA[t] = packed2[t * 2 + 0];
        sBsk[t + 4] = packed2[t * 2 + 1];
        float4 c = colors[t];
        scol[t] = c;
        if (c.w != 1.0f) sflag = 1;    // benign race, same value
    }
    __syncthreads();
    bool fast = (sflag == 0);

    int cnt = valid ? h0.x : 0;
    float cr = bg[0], cg = bg[1], cb = bg[2];
    int win = -1;

#define TESTS(eidx)                                                            \
    {                                                                          \
        int e = (eidx);                                                        \
        float4 A = sA[e];                                                      \
        float4 Bv = sBsk[e + 4];                                               \
        CORE_EVAL(A, Bv);                                                      \
        if (fast) {                                                            \
            if (s2 <= Bv.x) win = e;   /* ascending order: later = winner */   \
        } else {                                                               \
            float4 C = scol[e];                                                \
            float a = (s2 <= Bv.x) ? C.w : 0.0f;                               \
            float om = __fsub_rn(1.0f, a);                                     \
            cr = __fadd_rn(__fmul_rn(cr, om), __fmul_rn(C.x, a));              \
            cg = __fadd_rn(__fmul_rn(cg, om), __fmul_rn(C.y, a));              \
            cb = __fadd_rn(__fmul_rn(cb, om), __fmul_rn(C.z, a));              \
        }                                                                      \
    }

    if (cnt != SENT) {
        if (cnt > 0) TESTS(h0.y);
        if (cnt > 1) TESTS(h0.z);
        if (cnt > 2) TESTS(h0.w);
        if (cnt > 3) {
            int4 h1 = *(const int4*)(srow + 4);
            TESTS(h1.x);
            if (cnt > 4) TESTS(h1.y);
            if (cnt > 5) TESTS(h1.z);
            if (cnt > 6) TESTS(h1.w);
            if (cnt > 7) {
                int4 h2 = *(const int4*)(srow + 8);
                TESTS(h2.x);
                if (cnt > 8) TESTS(h2.y);
                if (cnt > 9) TESTS(h2.z);
                if (cnt > 10) TESTS(h2.w);
                if (cnt > 11) {
                    int4 h3 = *(const int4*)(srow + 12);
                    TESTS(h3.x);
                    if (cnt > 12) TESTS(h3.y);
                    if (cnt > 13) TESTS(h3.z);
                    if (cnt > 14) TESTS(h3.w);
                }
            }
        }
    } else {
        // rare overflow subcell: walk the full parent list
        const int* prow = etab + (size_t)parent * EROW;
        int pcnt = prow[0];
        for (int s = 0; s < pcnt; ++s) TESTS(prow[1 + s]);
    }
#undef TESTS

    if (valid) {
        if (fast && win >= 0) {
            float4 C = scol[win];
            cr = C.x; cg = C.y; cb = C.z;
        }
        out[(size_t)i * 3 + 0] = cr;
        out[(size_t)i * 3 + 1] = cg;
        out[(size_t)i * 3 + 2] = cb;
    }
}

// ---------------------------------------------------------------------------
// Fallback render (round-4 path) if ws_size is too small for the subgrid.
// ---------------------------------------------------------------------------
__global__ __launch_bounds__(1024) void render_fb(const float2* __restrict__ xs,
                                                  const float4* __restrict__ packed2,
                                                  const float4* __restrict__ colors,
                                                  const int* __restrict__ etab,
                                                  const float* __restrict__ bg,
                                                  float* __restrict__ out, int n, int nprim) {
    __shared__ float4 sAB[MAXPRIM * 2];
    __shared__ float4 scol[MAXPRIM];
    __shared__ int sflag;
    if (threadIdx.x == 0) sflag = 0;
    __syncthreads();

    int i = blockIdx.x * 1024 + threadIdx.x;
    bool valid = i < n;
    float px = 0.0f, py = 0.0f;
    int row = 0;
    int4 c0 = make_int4(0, 0, 0, 0), c1 = make_int4(0, 0, 0, 0);
    if (valid) {
        float2 pxy = xs[i];
        px = pxy.x; py = pxy.y;
        int ix = (int)__fmul_rn(px, (float)GRIDN);
        ix = min(max(ix, 0), GRIDN - 1);
        int iy = (int)__fmul_rn(py, (float)GRIDN);
        iy = min(max(iy, 0), GRIDN - 1);
        row = (ix * GRIDN + iy) * EROW;
        c0 = *(const int4*)(etab + row);
        c1 = *(const int4*)(etab + row + 4);
    }
    for (int t = threadIdx.x; t < nprim; t += 1024) {
        sAB[t * 2 + 0] = packed2[t * 2 + 0];
        sAB[t * 2 + 1] = packed2[t * 2 + 1];
        float4 c = colors[t];
        scol[t] = c;
        if (c.w != 1.0f) sflag = 1;
    }
    __syncthreads();
    int cnt = valid ? c0.x : 0;
    float cr = bg[0], cg = bg[1], cb = bg[2];
    int win = -1;
    bool fast = (sflag == 0);
#define TEST(pidx)                                                             \
    {                                                                          \
        int p = (pidx);                                                        \
        float4 A = sAB[p * 2 + 0];                                             \
        float4 Bv = sAB[p * 2 + 1];                                            \
        CORE_EVAL(A, Bv);                                                      \
        if (fast) {                                                            \
            if (s2 <= Bv.x) win = p;                                           \
        } else {                                                               \
            float4 C = scol[p];                                                \
            float a = (s2 <= Bv.x) ? C.w : 0.0f;                               \
            float om = __fsub_rn(1.0f, a);                                     \
            cr = __fadd_rn(__fmul_rn(cr, om), __fmul_rn(C.x, a));              \
            cg = __fadd_rn(__fmul_rn(cg, om), __fmul_rn(C.y, a));              \
            cb = __fadd_rn(__fmul_rn(cb, om), __fmul_rn(C.z, a));              \
        }                                                                      \
    }
    if (cnt > 0) TEST(c0.y);
    if (cnt > 1) TEST(c0.z);
    if (cnt > 2) TEST(c0.w);
    if (cnt > 3) TEST(c1.x);
    if (cnt > 4) TEST(c1.y);
    if (cnt > 5) TEST(c1.z);
    if (cnt > 6) TEST(c1.w);
    for (int base = 7; base < cnt; base += 4) {
        int4 c = *(const int4*)(etab + row + 1 + base);
        if (base + 0 < cnt) TEST(c.x);
        if (base + 1 < cnt) TEST(c.y);
        if (base + 2 < cnt) TEST(c.z);
        if (base + 3 < cnt) TEST(c.w);
    }
#undef TEST
    if (valid) {
        if (fast && win >= 0) {
            float4 C = scol[win];
            cr = C.x; cg = C.y; cb = C.z;
        }
        out[(size_t)i * 3 + 0] = cr;
        out[(size_t)i * 3 + 1] = cg;
        out[(size_t)i * 3 + 2] = cb;
    }
}

extern "C" void kernel_launch(void* const* d_in, const int* in_sizes, int n_in,
                              void* d_out, int out_size, void* d_ws, size_t ws_size,
                              hipStream_t stream) {
    const float* x  = (const float*)d_in[0];
    const float* cp = (const float*)d_in[1];
    const float* sw = (const float*)d_in[2];
    const float* fc = (const float*)d_in[3];
    const float* op = (const float*)d_in[4];
    const float* bg = (const float*)d_in[5];
    float* out = (float*)d_out;

    int npts  = in_sizes[0] / 2;
    int nprim = in_sizes[2];

    char* ws = (char*)d_ws;
    float4* packed2 = (float4*)(ws + WS_PACKED2);
    float4* colors  = (float4*)(ws + WS_COLORS);
    float4* aabb_g  = (float4*)(ws + WS_AABB);
    int* etab       = (int*)(ws + WS_ETAB);
    int* subtab     = (int*)(ws + WS_SUBTAB);

    size_t need = (size_t)WS_SUBTAB + 65536u * SROW * 4u;
    bool use_sub = (ws_size >= need);

    prep<<<GRIDN * GRIDN / 16, 1024, 0, stream>>>(cp, sw, fc, op, packed2, colors,
                                                  aabb_g, etab, nprim);
    if (use_sub) {
        build_sub<<<64, 1024, 0, stream>>>(aabb_g, etab, subtab);
        render_sub<<<(npts + 1023) / 1024, 1024, 0, stream>>>((const float2*)x, packed2,
                                                              colors, etab, subtab, bg,
                                                              out, npts, nprim);
    } else {
        render_fb<<<(npts + 1023) / 1024, 1024, 0, stream>>>((const float2*)x, packed2,
                                                             colors, etab, bg, out,
                                                             npts, nprim);
    }
}

// Round 7
// 56.316 us; speedup vs baseline: 5.9819x; 1.2422x over previous
//
#include <hip/hip_runtime.h>
#include <math.h>

#define GRIDN 64
#define MAXE 32
#define MAXPRIM 1024
#define EROW 36        // parent row: [cnt, e0..e31, pad x3]
#define SCAP2 15
#define SENTV 0xFFFF

// workspace layout (bytes)
#define WS_PACKED2   0u            // 1024*32
#define WS_COLORS    32768u        // 1024*16
#define WS_ETAB      49152u        // 4096*36*4 = 589824 -> ends 638976
#define WS_SUBTAB    655360u       // 65536*32 = 2 MB -> ends 2752512

// exact core: t = rn(td/denom) (double-recip mul), s2 <= Tf <=> rn(sqrt(s2)) <= w
#define CORE_EVAL(A, Bv)                                                         \
    float relx = __fsub_rn(px, A.x);                                             \
    float rely = __fsub_rn(py, A.y);                                             \
    float td = __fadd_rn(__fmul_rn(relx, A.z), __fmul_rn(rely, A.w));            \
    double inv = __hiloint2double(__float_as_int(Bv.z), __float_as_int(Bv.y));   \
    float tt = (float)((double)td * inv);                                        \
    tt = fminf(fmaxf(tt, 0.0f), 1.0f);                                           \
    float qx = __fsub_rn(relx, __fmul_rn(tt, A.z));                              \
    float qy = __fsub_rn(rely, __fmul_rn(tt, A.w));                              \
    float s2 = __fadd_rn(__fmul_rn(qx, qx), __fmul_rn(qy, qy));

// ---------------------------------------------------------------------------
// Kernel 1: prep — parent grid build (one wave per cell, AABBs in LDS);
// block 0 packs prim records.  packed2[p*2+1] = (Tf, inv_lo, inv_hi, w).
// ---------------------------------------------------------------------------
__global__ __launch_bounds__(1024) void prep(const float* __restrict__ cp,
                                             const float* __restrict__ sw,
                                             const float* __restrict__ fc,
                                             const float* __restrict__ op,
                                             float4* __restrict__ packed2,
                                             float4* __restrict__ colors,
                                             int* __restrict__ etab, int nprim) {
    __shared__ float4 saabb[MAXPRIM];
    int tid = threadIdx.x;
    for (int p = tid; p < nprim; p += 1024) {
        float x0 = cp[p * 6 + 0], y0 = cp[p * 6 + 1];
        float x1 = cp[p * 6 + 2], y1 = cp[p * 6 + 3];
        float w = sw[p];
        saabb[p] = make_float4(__fsub_rn(fminf(x0, x1), w), __fadd_rn(fmaxf(x0, x1), w),
                               __fsub_rn(fminf(y0, y1), w), __fadd_rn(fmaxf(y0, y1), w));
    }
    __syncthreads();

    int wid = tid >> 6, lane = tid & 63;
    int cell = blockIdx.x * 16 + wid;
    int ixc = cell >> 6, iyc = cell & 63;
    float lox = (float)ixc * (1.0f / GRIDN);
    float hix = (float)(ixc + 1) * (1.0f / GRIDN);
    float loy = (float)iyc * (1.0f / GRIDN);
    float hiy = (float)(iyc + 1) * (1.0f / GRIDN);
    int total = 0;
    int* row = etab + (size_t)cell * EROW;
    for (int base = 0; base < nprim; base += 64) {
        int p = base + lane;
        bool ov = false;
        if (p < nprim) {
            float4 bb = saabb[p];
            ov = (bb.x < hix) && (bb.y >= lox) && (bb.z < hiy) && (bb.w >= loy);
        }
        unsigned long long m = __ballot(ov);
        if (ov) {
            int pos = total + (int)__popcll(m & ((1ull << lane) - 1ull));
            if (pos < MAXE) row[1 + pos] = p;
        }
        total += (int)__popcll(m);
    }
    if (lane == 0) row[0] = total < MAXE ? total : MAXE;

    if (blockIdx.x == 0) {
        for (int p = tid; p < nprim; p += 1024) {
            float x0 = cp[p * 6 + 0], y0 = cp[p * 6 + 1];
            float x1 = cp[p * 6 + 2], y1 = cp[p * 6 + 3];
            float w = sw[p];
            float dx = __fsub_rn(x1, x0);
            float dy = __fsub_rn(y1, y0);
            float dd = __fadd_rn(__fmul_rn(dx, dx), __fmul_rn(dy, dy));
            float denom = fmaxf(dd, 1e-12f);
            double inv = 1.0 / (double)denom;
            unsigned wb = __float_as_uint(w);
            bool even = (wb & 1u) == 0u;
            float wn = __uint_as_float(wb + 1u);
            double md = 0.5 * ((double)w + (double)wn);
            double m2 = md * md;
            float Tf = (float)m2;
            if ((double)Tf > m2) Tf = __uint_as_float(__float_as_uint(Tf) - 1u);
            if (!even && (double)Tf == m2) Tf = __uint_as_float(__float_as_uint(Tf) - 1u);
            unsigned long long ib = __double_as_longlong(inv);
            packed2[p * 2 + 0] = make_float4(x0, y0, dx, dy);
            packed2[p * 2 + 1] = make_float4(Tf,
                                             __uint_as_float((unsigned)(ib & 0xffffffffull)),
                                             __uint_as_float((unsigned)(ib >> 32)),
                                             w);
            colors[p] = make_float4(fc[p * 3 + 0], fc[p * 3 + 1], fc[p * 3 + 2], op[p]);
        }
    }
}

// ---------------------------------------------------------------------------
// Kernel 2: build 256x256 subgrid, EXACT capsule culling: keep prim iff the
// segment intersects the subcell rect dilated by (w + 1e-5) (f64 slab test).
// Conservative superset of "any point in subcell inside stroke" since ref's
// fp32 dist >= true min-dist - ~1e-8.  Row: u16 cnt | 15 x u16 entries (32 B).
// cnt > 15 -> sentinel 0xFFFF (render walks parent list).
// ---------------------------------------------------------------------------
__global__ __launch_bounds__(1024) void build_sub(const float4* __restrict__ packed2,
                                                  const int* __restrict__ etab,
                                                  unsigned short* __restrict__ subtab) {
    int t = blockIdx.x * 1024 + threadIdx.x;   // 64 x 1024 = 65536 subcells
    int parent = t >> 4;
    int sub = t & 15;
    int ix = parent >> 6, iy = parent & 63;
    int gx = ix * 4 + (sub >> 2), gy = iy * 4 + (sub & 3);
    double clx = (double)gx * (1.0 / 256.0);
    double chx = (double)(gx + 1) * (1.0 / 256.0);
    double cly = (double)gy * (1.0 / 256.0);
    double chy = (double)(gy + 1) * (1.0 / 256.0);
    const int* row = etab + (size_t)parent * EROW;
    int cnt = row[0];
    unsigned short* srow = subtab + (size_t)(gx * 256 + gy) * 16;
    int oc = 0;
    for (int s = 0; s < cnt; ++s) {
        int e = row[1 + s];
        float4 A = packed2[e * 2 + 0];
        float4 B = packed2[e * 2 + 1];
        double W = (double)B.w + 1e-5;
        double lx = clx - W, hx = chx + W, ly = cly - W, hy = chy + W;
        double ax = (double)A.x, ay = (double)A.y;
        double dx = (double)A.z, dy = (double)A.w;
        double t0 = 0.0, t1 = 1.0;
        bool ok = true;
        if (fabs(dx) > 1e-300) {
            double ta = (lx - ax) / dx, tb = (hx - ax) / dx;
            t0 = fmax(t0, fmin(ta, tb));
            t1 = fmin(t1, fmax(ta, tb));
        } else if (ax < lx || ax > hx) ok = false;
        if (ok) {
            if (fabs(dy) > 1e-300) {
                double ta = (ly - ay) / dy, tb = (hy - ay) / dy;
                t0 = fmax(t0, fmin(ta, tb));
                t1 = fmin(t1, fmax(ta, tb));
            } else if (ay < ly || ay > hy) ok = false;
        }
        if (ok && t0 <= t1) {
            if (oc < SCAP2) srow[1 + oc] = (unsigned short)e;
            ++oc;
        }
    }
    srow[0] = (oc <= SCAP2) ? (unsigned short)oc : (unsigned short)SENTV;
}

// ---------------------------------------------------------------------------
// per-prim test (exact core + fast/composite update)
// ---------------------------------------------------------------------------
__device__ __forceinline__ void test_prim(int e, float px, float py, bool fast,
                                          int& win, float& cr, float& cg, float& cb,
                                          const float4* sA, const float4* sBsk,
                                          const float4* scol) {
    float4 A = sA[e];
    float4 Bv = sBsk[e + 4];
    CORE_EVAL(A, Bv);
    if (fast) {
        if (s2 <= Bv.x) win = e;       // ascending order: later = winner
    } else {
        float4 C = scol[e];
        float a = (s2 <= Bv.x) ? C.w : 0.0f;
        float om = __fsub_rn(1.0f, a);
        cr = __fadd_rn(__fmul_rn(cr, om), __fmul_rn(C.x, a));
        cg = __fadd_rn(__fmul_rn(cg, om), __fmul_rn(C.y, a));
        cb = __fadd_rn(__fmul_rn(cb, om), __fmul_rn(C.z, a));
    }
}

// ---------------------------------------------------------------------------
// Kernel 3: render, 2 points per thread. One 32B row tap per point (2 int4,
// same 64B line). Prim records in LDS (B skewed +64B).
// ---------------------------------------------------------------------------
__global__ __launch_bounds__(1024) void render_sub2(const float4* __restrict__ xs4,
                                                    const float4* __restrict__ packed2,
                                                    const float4* __restrict__ colors,
                                                    const int* __restrict__ etab,
                                                    const int* __restrict__ subtab,
                                                    const float* __restrict__ bg,
                                                    float* __restrict__ out, int n, int nprim) {
    __shared__ float4 sA[MAXPRIM];
    __shared__ float4 sBsk[MAXPRIM + 4];
    __shared__ float4 scol[MAXPRIM];
    __shared__ int sflag;
    if (threadIdx.x == 0) sflag = 0;
    __syncthreads();

    int tpair = blockIdx.x * 1024 + threadIdx.x;   // handles points 2*tpair, 2*tpair+1
    long long p0 = (long long)tpair * 2;
    bool v0 = p0 < n, v1 = p0 + 1 < n;

    float4 P = make_float4(0.f, 0.f, 0.f, 0.f);
    if (v0) P = xs4[tpair];                        // (x0,y0,x1,y1) coalesced
    float pxs[2] = {P.x, P.z};
    float pys[2] = {P.y, P.w};
    bool vs[2] = {v0, v1};
    int parentv[2] = {0, 0};
    int4 lo[2], hi[2];
    lo[0] = lo[1] = make_int4(0, 0, 0, 0);
    hi[0] = hi[1] = make_int4(0, 0, 0, 0);

#pragma unroll
    for (int j = 0; j < 2; ++j) {
        if (vs[j]) {
            float px = pxs[j], py = pys[j];
            int ix = (int)__fmul_rn(px, (float)GRIDN);
            ix = min(max(ix, 0), GRIDN - 1);
            int iy = (int)__fmul_rn(py, (float)GRIDN);
            iy = min(max(iy, 0), GRIDN - 1);
            parentv[j] = ix * GRIDN + iy;
            int sx = (int)__fmul_rn(px, 256.0f) - ix * 4;
            sx = min(max(sx, 0), 3);
            int sy = (int)__fmul_rn(py, 256.0f) - iy * 4;
            sy = min(max(sy, 0), 3);
            const int* srow = subtab + (size_t)((ix * 4 + sx) * 256 + (iy * 4 + sy)) * 8;
            lo[j] = *(const int4*)srow;
            hi[j] = *(const int4*)(srow + 4);
        }
    }

    for (int t = threadIdx.x; t < nprim; t += 1024) {
        sA[t] = packed2[t * 2 + 0];
        sBsk[t + 4] = packed2[t * 2 + 1];
        float4 c = colors[t];
        scol[t] = c;
        if (c.w != 1.0f) sflag = 1;    // benign race, same value
    }
    __syncthreads();
    bool fast = (sflag == 0);
    float bgr = bg[0], bgg = bg[1], bgb = bg[2];

    float oc6[6];
#pragma unroll
    for (int j = 0; j < 2; ++j) {
        float px = pxs[j], py = pys[j];
        float cr = bgr, cg = bgg, cb = bgb;
        int win = -1;
        unsigned w0 = (unsigned)lo[j].x;
        int cnt = vs[j] ? (int)(w0 & 0xffffu) : 0;
        if (cnt != SENTV) {
            unsigned wy = (unsigned)lo[j].y, wz = (unsigned)lo[j].z, ww = (unsigned)lo[j].w;
            unsigned hx = (unsigned)hi[j].x, hy = (unsigned)hi[j].y;
            unsigned hz = (unsigned)hi[j].z, hw = (unsigned)hi[j].w;
            if (cnt > 0)  test_prim((int)(w0 >> 16),      px, py, fast, win, cr, cg, cb, sA, sBsk, scol);
            if (cnt > 1)  test_prim((int)(wy & 0xffffu),  px, py, fast, win, cr, cg, cb, sA, sBsk, scol);
            if (cnt > 2)  test_prim((int)(wy >> 16),      px, py, fast, win, cr, cg, cb, sA, sBsk, scol);
            if (cnt > 3)  test_prim((int)(wz & 0xffffu),  px, py, fast, win, cr, cg, cb, sA, sBsk, scol);
            if (cnt > 4)  test_prim((int)(wz >> 16),      px, py, fast, win, cr, cg, cb, sA, sBsk, scol);
            if (cnt > 5)  test_prim((int)(ww & 0xffffu),  px, py, fast, win, cr, cg, cb, sA, sBsk, scol);
            if (cnt > 6)  test_prim((int)(ww >> 16),      px, py, fast, win, cr, cg, cb, sA, sBsk, scol);
            if (cnt > 7)  test_prim((int)(hx & 0xffffu),  px, py, fast, win, cr, cg, cb, sA, sBsk, scol);
            if (cnt > 8)  test_prim((int)(hx >> 16),      px, py, fast, win, cr, cg, cb, sA, sBsk, scol);
            if (cnt > 9)  test_prim((int)(hy & 0xffffu),  px, py, fast, win, cr, cg, cb, sA, sBsk, scol);
            if (cnt > 10) test_prim((int)(hy >> 16),      px, py, fast, win, cr, cg, cb, sA, sBsk, scol);
            if (cnt > 11) test_prim((int)(hz & 0xffffu),  px, py, fast, win, cr, cg, cb, sA, sBsk, scol);
            if (cnt > 12) test_prim((int)(hz >> 16),      px, py, fast, win, cr, cg, cb, sA, sBsk, scol);
            if (cnt > 13) test_prim((int)(hw & 0xffffu),  px, py, fast, win, cr, cg, cb, sA, sBsk, scol);
            if (cnt > 14) test_prim((int)(hw >> 16),      px, py, fast, win, cr, cg, cb, sA, sBsk, scol);
        } else {
            const int* prow = etab + (size_t)parentv[j] * EROW;
            int pcnt = prow[0];
            for (int s = 0; s < pcnt; ++s)
                test_prim(prow[1 + s], px, py, fast, win, cr, cg, cb, sA, sBsk, scol);
        }
        if (fast && win >= 0) {
            float4 C = scol[win];
            cr = C.x; cg = C.y; cb = C.z;
        }
        oc6[j * 3 + 0] = cr;
        oc6[j * 3 + 1] = cg;
        oc6[j * 3 + 2] = cb;
    }

    // 24 B consecutive per thread -> 3 x float2 (8B-aligned), coalesced
    float* ob = out + (size_t)tpair * 6;
    if (v1) {
        *(float2*)(ob + 0) = make_float2(oc6[0], oc6[1]);
        *(float2*)(ob + 2) = make_float2(oc6[2], oc6[3]);
        *(float2*)(ob + 4) = make_float2(oc6[4], oc6[5]);
    } else if (v0) {
        ob[0] = oc6[0]; ob[1] = oc6[1]; ob[2] = oc6[2];
    }
}

// ---------------------------------------------------------------------------
// Fallback render (round-4 path) if ws_size is too small for the subgrid.
// ---------------------------------------------------------------------------
__global__ __launch_bounds__(1024) void render_fb(const float2* __restrict__ xs,
                                                  const float4* __restrict__ packed2,
                                                  const float4* __restrict__ colors,
                                                  const int* __restrict__ etab,
                                                  const float* __restrict__ bg,
                                                  float* __restrict__ out, int n, int nprim) {
    __shared__ float4 sA[MAXPRIM];
    __shared__ float4 sBsk[MAXPRIM + 4];
    __shared__ float4 scol[MAXPRIM];
    __shared__ int sflag;
    if (threadIdx.x == 0) sflag = 0;
    __syncthreads();

    int i = blockIdx.x * 1024 + threadIdx.x;
    bool valid = i < n;
    float px = 0.0f, py = 0.0f;
    int row = 0;
    int4 c0 = make_int4(0, 0, 0, 0), c1 = make_int4(0, 0, 0, 0);
    if (valid) {
        float2 pxy = xs[i];
        px = pxy.x; py = pxy.y;
        int ix = (int)__fmul_rn(px, (float)GRIDN);
        ix = min(max(ix, 0), GRIDN - 1);
        int iy = (int)__fmul_rn(py, (float)GRIDN);
        iy = min(max(iy, 0), GRIDN - 1);
        row = (ix * GRIDN + iy) * EROW;
        c0 = *(const int4*)(etab + row);
        c1 = *(const int4*)(etab + row + 4);
    }
    for (int t = threadIdx.x; t < nprim; t += 1024) {
        sA[t] = packed2[t * 2 + 0];
        sBsk[t + 4] = packed2[t * 2 + 1];
        float4 c = colors[t];
        scol[t] = c;
        if (c.w != 1.0f) sflag = 1;
    }
    __syncthreads();
    int cnt = valid ? c0.x : 0;
    float cr = bg[0], cg = bg[1], cb = bg[2];
    int win = -1;
    bool fast = (sflag == 0);
    if (cnt > 0) test_prim(c0.y, px, py, fast, win, cr, cg, cb, sA, sBsk, scol);
    if (cnt > 1) test_prim(c0.z, px, py, fast, win, cr, cg, cb, sA, sBsk, scol);
    if (cnt > 2) test_prim(c0.w, px, py, fast, win, cr, cg, cb, sA, sBsk, scol);
    if (cnt > 3) test_prim(c1.x, px, py, fast, win, cr, cg, cb, sA, sBsk, scol);
    if (cnt > 4) test_prim(c1.y, px, py, fast, win, cr, cg, cb, sA, sBsk, scol);
    if (cnt > 5) test_prim(c1.z, px, py, fast, win, cr, cg, cb, sA, sBsk, scol);
    if (cnt > 6) test_prim(c1.w, px, py, fast, win, cr, cg, cb, sA, sBsk, scol);
    for (int base = 7; base < cnt; base += 4) {
        int4 c = *(const int4*)(etab + row + 1 + base);
        if (base + 0 < cnt) test_prim(c.x, px, py, fast, win, cr, cg, cb, sA, sBsk, scol);
        if (base + 1 < cnt) test_prim(c.y, px, py, fast, win, cr, cg, cb, sA, sBsk, scol);
        if (base + 2 < cnt) test_prim(c.z, px, py, fast, win, cr, cg, cb, sA, sBsk, scol);
        if (base + 3 < cnt) test_prim(c.w, px, py, fast, win, cr, cg, cb, sA, sBsk, scol);
    }
    if (valid) {
        if (fast && win >= 0) {
            float4 C = scol[win];
            cr = C.x; cg = C.y; cb = C.z;
        }
        out[(size_t)i * 3 + 0] = cr;
        out[(size_t)i * 3 + 1] = cg;
        out[(size_t)i * 3 + 2] = cb;
    }
}

extern "C" void kernel_launch(void* const* d_in, const int* in_sizes, int n_in,
                              void* d_out, int out_size, void* d_ws, size_t ws_size,
                              hipStream_t stream) {
    const float* x  = (const float*)d_in[0];
    const float* cp = (const float*)d_in[1];
    const float* sw = (const float*)d_in[2];
    const float* fc = (const float*)d_in[3];
    const float* op = (const float*)d_in[4];
    const float* bg = (const float*)d_in[5];
    float* out = (float*)d_out;

    int npts  = in_sizes[0] / 2;
    int nprim = in_sizes[2];

    char* ws = (char*)d_ws;
    float4* packed2 = (float4*)(ws + WS_PACKED2);
    float4* colors  = (float4*)(ws + WS_COLORS);
    int* etab       = (int*)(ws + WS_ETAB);
    unsigned short* subtab = (unsigned short*)(ws + WS_SUBTAB);

    size_t need = (size_t)WS_SUBTAB + 65536u * 32u;
    bool use_sub = (ws_size >= need);

    prep<<<GRIDN * GRIDN / 16, 1024, 0, stream>>>(cp, sw, fc, op, packed2, colors,
                                                  etab, nprim);
    if (use_sub) {
        build_sub<<<64, 1024, 0, stream>>>(packed2, etab, subtab);
        int npairs = (npts + 1) / 2;
        render_sub2<<<(npairs + 1023) / 1024, 1024, 0, stream>>>((const float4*)x, packed2,
                                                                 colors, etab, (const int*)subtab,
                                                                 bg, out, npts, nprim);
    } else {
        render_fb<<<(npts + 1023) / 1024, 1024, 0, stream>>>((const float2*)x, packed2,
                                                             colors, etab, bg, out,
                                                             npts, nprim);
    }
}